// Round 1
// baseline (1623.415 us; speedup 1.0000x reference)
//
#include <hip/hip_runtime.h>
#include <hip/hip_fp16.h>

#define B_ 4
#define L_ 2048
#define S_ 2048
#define H_ 8
#define E_ 64
#define D_ 64
#define ROWS 8            // Q-rows per block (4 waves x 2 rows)
#define NT 32             // S/64 tiles
#define KSEL0 1372u       // int(2048*0.67)
#define KSEL1 1536u       // int(2048*0.75)
#define KSEL2 1638u       // int(2048*0.80)
#define WSCALE 4096.0f

__device__ __forceinline__ float bcastf(float v, int lane) {
  return __uint_as_float((unsigned)__builtin_amdgcn_readlane((int)__float_as_uint(v), lane));
}

// monotone 16-bit key from fp16 bits (ascending float -> ascending uint)
__device__ __forceinline__ unsigned ou16_of(unsigned hb) {
  return hb ^ ((hb & 0x8000u) ? 0xFFFFu : 0x8000u);
}

// wave-private 256-bin histogram scan: find digit d with above(d) < k <= above(d)+cnt(d)
// returns (d<<16) | (k - above(d))
__device__ __forceinline__ unsigned sel_digit(const unsigned* histw, unsigned k, int lane) {
  uint4 h = ((const uint4*)histw)[lane];   // bins 4l..4l+3
  unsigned s4 = h.x + h.y + h.z + h.w;
  unsigned p = s4;                          // inclusive suffix over lanes
  #pragma unroll
  for (int off = 1; off < 64; off <<= 1) {
    int sl = lane + off;
    unsigned t = (unsigned)__shfl((int)p, sl < 64 ? sl : lane, 64);
    p += (sl < 64) ? t : 0u;
  }
  unsigned a3 = p - s4;          // count in bins above 4l+3
  unsigned a2 = a3 + h.w;
  unsigned a1 = a2 + h.z;
  unsigned a0 = a1 + h.y;
  int d = -1; unsigned nk = 0;
  if (a3 < k && a3 + h.w >= k)      { d = 4*lane+3; nk = k - a3; }
  else if (a2 < k && a2 + h.z >= k) { d = 4*lane+2; nk = k - a2; }
  else if (a1 < k && a1 + h.y >= k) { d = 4*lane+1; nk = k - a1; }
  else if (a0 < k && a0 + h.x >= k) { d = 4*lane+0; nk = k - a0; }
  unsigned long long mb = __ballot(d >= 0);
  int src = __ffsll(mb) - 1;
  unsigned pack = ((unsigned)d << 16) | nk;
  return (unsigned)__shfl((int)pack, src, 64);
}

extern "C" __global__ __launch_bounds__(256, 3)
void nma_kernel(const float* __restrict__ Q, const float* __restrict__ K,
                const float* __restrict__ V, const float* __restrict__ AW,
                float* __restrict__ Out)
{
  __shared__ __half sc[ROWS][S_];                    // scores, later weights (32 KB)
  __shared__ alignas(16) unsigned stagebuf[4096];    // 16 KB: K/V staging OR histograms
  float4* stg4 = (float4*)stagebuf;
  float*  stgf = (float*)stagebuf;

  const int tid  = threadIdx.x;
  const int w    = tid >> 6;      // wave 0..3
  const int lane = tid & 63;

  // XCD-aware swizzle (grid 8192 = 8 * 1024): consecutive logical blocks -> same XCD
  int bid = blockIdx.x;
  int lb  = (bid & 7) * 1024 + (bid >> 3);
  int bh  = lb >> 8;              // 256 blocks per (b,h)
  int b   = bh >> 3, hh = bh & 7;
  int l0  = (lb & 255) * ROWS;

  const float* Qb = Q + (((size_t)b * L_ + l0) * H_ + hh) * E_;
  const float* Kb = K + ((size_t)b * S_ * H_ + hh) * E_;
  const float* Vb = V + ((size_t)b * S_ * H_ + hh) * E_;

  // wave w owns rows 2w, 2w+1; lane holds q[e=lane], pre-scaled by 1/sqrt(E)
  float qv0 = Qb[(2*w + 0) * (H_*E_) + lane] * 0.125f;
  float qv1 = Qb[(2*w + 1) * (H_*E_) + lane] * 0.125f;

  // ================= QK^T =================
  for (int st = 0; st < NT; ++st) {
    __syncthreads();
    // stage K tile (64 s x 64 e) quad-transposed with XOR swizzle:
    // quad (q4, s) at float4 index q4*64 + (s ^ (q4&7))
    #pragma unroll
    for (int i = 0; i < 4; ++i) {
      int idx = i * 256 + tid;
      int q4 = idx & 15, sr = idx >> 4;
      float4 kv = *(const float4*)(Kb + (size_t)(st*64 + sr) * (H_*E_) + q4*4);
      stg4[q4*64 + (sr ^ (q4 & 7))] = kv;
    }
    __syncthreads();
    float a0A=0.f, a0B=0.f, a1A=0.f, a1B=0.f;
    #pragma unroll
    for (int q4 = 0; q4 < 16; ++q4) {
      float4 kq = stg4[q4*64 + (lane ^ (q4 & 7))];   // K[st*64+lane][4q4..4q4+3]
      float q00 = bcastf(qv0, 4*q4+0), q01 = bcastf(qv0, 4*q4+1);
      float q02 = bcastf(qv0, 4*q4+2), q03 = bcastf(qv0, 4*q4+3);
      float q10 = bcastf(qv1, 4*q4+0), q11 = bcastf(qv1, 4*q4+1);
      float q12 = bcastf(qv1, 4*q4+2), q13 = bcastf(qv1, 4*q4+3);
      a0A = fmaf(q00, kq.x, a0A); a0A = fmaf(q01, kq.y, a0A);
      a0B = fmaf(q02, kq.z, a0B); a0B = fmaf(q03, kq.w, a0B);
      a1A = fmaf(q10, kq.x, a1A); a1A = fmaf(q11, kq.y, a1A);
      a1B = fmaf(q12, kq.z, a1B); a1B = fmaf(q13, kq.w, a1B);
    }
    sc[2*w+0][st*64 + lane] = __float2half(a0A + a0B);
    sc[2*w+1][st*64 + lane] = __float2half(a1A + a1B);
  }
  __syncthreads();   // all scores written; stagebuf free for histograms

  const float aw0 = AW[0], aw1 = AW[1], aw2 = AW[2];

  // ============ selection + softmax-band weights, per wave's 2 rows ============
  #pragma unroll
  for (int rr = 0; rr < 2; ++rr) {
    int r = 2*w + rr;
    unsigned* histw = stagebuf + w * 768;      // per-wave region (3 KB)
    unsigned kk0 = KSEL0, kk1 = KSEL1, kk2 = KSEL2;

    // ---- radix round 1 (high byte) ----
    for (int t = lane; t < 256; t += 64) histw[t] = 0;
    __syncthreads();
    #pragma unroll 8
    for (int j = 0; j < 32; ++j) {
      unsigned hb = __half_as_ushort(sc[r][j*64 + lane]);
      atomicAdd(&histw[ou16_of(hb) >> 8], 1u);
    }
    __syncthreads();
    unsigned p0 = sel_digit(histw, kk0, lane);
    unsigned p1 = sel_digit(histw, kk1, lane);
    unsigned p2 = sel_digit(histw, kk2, lane);
    unsigned d0 = p0 >> 16, d1 = p1 >> 16, d2 = p2 >> 16;
    kk0 = p0 & 0xFFFFu; kk1 = p1 & 0xFFFFu; kk2 = p2 & 0xFFFFu;
    __syncthreads();

    // ---- radix round 2 (low byte), 3 restricted histograms ----
    for (int t = lane; t < 768; t += 64) histw[t] = 0;
    __syncthreads();
    #pragma unroll 4
    for (int j = 0; j < 32; ++j) {
      unsigned hb = __half_as_ushort(sc[r][j*64 + lane]);
      unsigned ou = ou16_of(hb);
      unsigned hi = ou >> 8, lo = ou & 255u;
      if (hi == d0) atomicAdd(&histw[lo], 1u);
      if (hi == d1) atomicAdd(&histw[256 + lo], 1u);
      if (hi == d2) atomicAdd(&histw[512 + lo], 1u);
    }
    __syncthreads();
    unsigned T1 = (d0 << 8) | (sel_digit(histw,       kk0, lane) >> 16);
    unsigned T2 = (d1 << 8) | (sel_digit(histw + 256, kk1, lane) >> 16);
    unsigned T3 = (d2 << 8) | (sel_digit(histw + 512, kk2, lane) >> 16);
    __syncthreads();

    // ---- row max ----
    float mx = -3.0e38f;
    #pragma unroll 8
    for (int j = 0; j < 32; ++j)
      mx = fmaxf(mx, __half2float(sc[r][j*64 + lane]));
    #pragma unroll
    for (int off = 32; off; off >>= 1)
      mx = fmaxf(mx, __shfl_xor(mx, off, 64));

    // ---- Z1..Z3 (nested selected sets) ----
    float z1 = 0.f, z2 = 0.f, z3 = 0.f;
    #pragma unroll 8
    for (int j = 0; j < 32; ++j) {
      __half hv = sc[r][j*64 + lane];
      unsigned ou = ou16_of(__half_as_ushort(hv));
      float e = __expf(__half2float(hv) - mx);
      if (ou >= T3) z3 += e;
      if (ou >= T2) z2 += e;
      if (ou >= T1) z1 += e;
    }
    #pragma unroll
    for (int off = 32; off; off >>= 1) {
      z1 += __shfl_xor(z1, off, 64);
      z2 += __shfl_xor(z2, off, 64);
      z3 += __shfl_xor(z3, off, 64);
    }
    float A3 = aw2 / z3;
    float A2 = aw1 / z2 + A3;
    float A1 = aw0 / z1 + A2;
    A1 *= WSCALE; A2 *= WSCALE; A3 *= WSCALE;

    // ---- overwrite scores with weights w = exp(s-m) * band_coef * WSCALE ----
    #pragma unroll 8
    for (int j = 0; j < 32; ++j) {
      __half hv = sc[r][j*64 + lane];
      unsigned ou = ou16_of(__half_as_ushort(hv));
      float e = __expf(__half2float(hv) - mx);
      float c = (ou >= T1) ? A1 : (ou >= T2) ? A2 : (ou >= T3) ? A3 : 0.f;
      sc[r][j*64 + lane] = __float2half(e * c);
    }
  }

  // ================= PV =================
  float acc0a = 0.f, acc0b = 0.f, acc1a = 0.f, acc1b = 0.f;
  for (int st = 0; st < NT; ++st) {
    __syncthreads();
    // stage V tile row-major [64 s][64 d]
    #pragma unroll
    for (int i = 0; i < 4; ++i) {
      int idx = i * 256 + tid;
      int q4 = idx & 15, sr = idx >> 4;
      stg4[sr*16 + q4] = *(const float4*)(Vb + (size_t)(st*64 + sr) * (H_*E_) + q4*4);
    }
    __syncthreads();
    float wr0 = __half2float(sc[2*w+0][st*64 + lane]);
    float wr1 = __half2float(sc[2*w+1][st*64 + lane]);
    #pragma unroll 8
    for (int si = 0; si < 64; si += 2) {
      float va = stgf[si*64 + lane];          // V[st*64+si][d=lane]
      float vb = stgf[(si+1)*64 + lane];
      float w0a = bcastf(wr0, si), w0b = bcastf(wr0, si+1);
      float w1a = bcastf(wr1, si), w1b = bcastf(wr1, si+1);
      acc0a = fmaf(w0a, va, acc0a); acc0b = fmaf(w0b, vb, acc0b);
      acc1a = fmaf(w1a, va, acc1a); acc1b = fmaf(w1b, vb, acc1b);
    }
  }

  const float inv = 1.0f / WSCALE;
  float* Ob = Out + (((size_t)b * L_ + l0) * H_ + hh) * D_;
  Ob[(2*w+0)*(H_*D_) + lane] = (acc0a + acc0b) * inv;
  Ob[(2*w+1)*(H_*D_) + lane] = (acc1a + acc1b) * inv;
}

extern "C" void kernel_launch(void* const* d_in, const int* in_sizes, int n_in,
                              void* d_out, int out_size, void* d_ws, size_t ws_size,
                              hipStream_t stream) {
  (void)in_sizes; (void)n_in; (void)d_ws; (void)ws_size; (void)out_size;
  const float* Q  = (const float*)d_in[0];
  const float* K  = (const float*)d_in[1];
  const float* V  = (const float*)d_in[2];
  const float* AW = (const float*)d_in[3];
  nma_kernel<<<dim3(B_ * H_ * (L_ / ROWS)), dim3(256), 0, stream>>>(
      Q, K, V, AW, (float*)d_out);
}

// Round 3
// 731.575 us; speedup vs baseline: 2.2191x; 2.2191x over previous
//
#include <hip/hip_runtime.h>
#include <hip/hip_fp16.h>

typedef _Float16 f16x8 __attribute__((ext_vector_type(8)));
typedef float f32x4 __attribute__((ext_vector_type(4)));

#define KSEL0 1372u   // int(2048*0.67)
#define KSEL1 1536u   // int(2048*0.75)
#define KSEL2 1638u   // int(2048*0.80)
#define WSC 16.0f

__device__ __forceinline__ unsigned ou16_of(unsigned hb) {
  return hb ^ ((hb & 0x8000u) ? 0xFFFFu : 0x8000u);
}
__device__ __forceinline__ unsigned ou16_inv(unsigned ou) {
  return (ou & 0x8000u) ? (ou ^ 0x8000u) : (ou ^ 0xFFFFu);
}
__device__ __forceinline__ unsigned pk2(float a, float b) {
  auto h = __builtin_amdgcn_cvt_pkrtz(a, b);   // __fp16 ext_vector_type(2)
  return __builtin_bit_cast(unsigned, h);
}
__device__ __forceinline__ unsigned shflx(unsigned v, int m) {
  return (unsigned)__shfl_xor((int)v, m, 64);
}

// exact k-th-largest digit select on a 256-bin histogram (wave-collective)
// returns (digit<<16) | (k remainder within digit)
__device__ __forceinline__ unsigned sel_digit(const unsigned* histw, unsigned k, int lane) {
  uint4 h = ((const uint4*)histw)[lane];   // bins 4l..4l+3
  unsigned s4 = h.x + h.y + h.z + h.w;
  unsigned p = s4;                          // inclusive suffix over lanes
  #pragma unroll
  for (int off = 1; off < 64; off <<= 1) {
    int sl = lane + off;
    unsigned t = (unsigned)__shfl((int)p, sl < 64 ? sl : lane, 64);
    p += (sl < 64) ? t : 0u;
  }
  unsigned a3 = p - s4;
  unsigned a2 = a3 + h.w;
  unsigned a1 = a2 + h.z;
  unsigned a0 = a1 + h.y;
  int d = -1; unsigned nk = 0;
  if (a3 < k && a3 + h.w >= k)      { d = 4*lane+3; nk = k - a3; }
  else if (a2 < k && a2 + h.z >= k) { d = 4*lane+2; nk = k - a2; }
  else if (a1 < k && a1 + h.y >= k) { d = 4*lane+1; nk = k - a1; }
  else if (a0 < k && a0 + h.x >= k) { d = 4*lane+0; nk = k - a0; }
  unsigned long long mb = __ballot(d >= 0);
  int src = __ffsll(mb) - 1;
  unsigned pack = ((unsigned)d << 16) | nk;
  return (unsigned)__shfl((int)pack, src, 64);
}

extern "C" __global__ __launch_bounds__(256, 2)
void nma_kernel(const float* __restrict__ Q, const float* __restrict__ K,
                const float* __restrict__ V, const float* __restrict__ AW,
                float* __restrict__ Out)
{
  // LDS: [0,64K) sc[16 rows][2048] fp16, swizzled byte^=((q&7)<<4)
  //      [64K,80K) union{ hist1[16][256] u32 ; Vt[64 d][128 s] fp16 swizzled }
  __shared__ __align__(16) char lds[81920];
  unsigned* binsU = (unsigned*)(lds + 65536);
  char* vtb = lds + 65536;

  const int tid  = threadIdx.x;
  const int w    = tid >> 6;
  const int lane = tid & 63;
  const int g    = lane >> 4;
  const int lx   = lane & 15;

  // XCD-aware bijective swizzle (4096 % 8 == 0): 512 consecutive per XCD
  int bid = blockIdx.x;
  int lb  = (bid & 7) * 512 + (bid >> 3);
  int bh  = lb >> 7;                 // 128 blocks per (b,h)
  int b   = bh >> 3, hh = bh & 7;
  int l0  = (lb & 127) << 4;         // 16 rows per block

  const float* Qb = Q + (((size_t)b * 2048 + l0) * 8 + hh) * 64;
  const float* Kb = K + ((size_t)b * 2048 * 8 + hh) * 64;
  const float* Vb = V + ((size_t)b * 2048 * 8 + hh) * 64;

  // ---- zero hist1 ----
  {
    uint4 z4 = {0u,0u,0u,0u};
    uint4* p = (uint4*)binsU;
    #pragma unroll
    for (int i = 0; i < 4; ++i) p[tid + 256*i] = z4;
  }

  // ---- Q A-frags (2 K-halves), scale 1/8 folded ----
  union FU { f16x8 v; unsigned u[4]; };
  FU qa0, qa1;
  {
    const float* qp = Qb + (size_t)lx * 512 + g * 8;
    float4 a = *(const float4*)(qp);
    float4 c = *(const float4*)(qp + 4);
    qa0.u[0] = pk2(a.x*0.125f, a.y*0.125f); qa0.u[1] = pk2(a.z*0.125f, a.w*0.125f);
    qa0.u[2] = pk2(c.x*0.125f, c.y*0.125f); qa0.u[3] = pk2(c.z*0.125f, c.w*0.125f);
    a = *(const float4*)(qp + 32);
    c = *(const float4*)(qp + 36);
    qa1.u[0] = pk2(a.x*0.125f, a.y*0.125f); qa1.u[1] = pk2(a.z*0.125f, a.w*0.125f);
    qa1.u[2] = pk2(c.x*0.125f, c.y*0.125f); qa1.u[3] = pk2(c.z*0.125f, c.w*0.125f);
  }
  __syncthreads();

  // ================= QK^T (MFMA, K direct from L2) + fused hist1 =================
  for (int t = 0; t < 32; ++t) {
    int ct = t * 4 + w;                 // col tile 0..127
    int s  = ct * 16 + lx;
    const float* kp = Kb + (size_t)s * 512 + g * 8;
    FU kb0, kb1;
    {
      float4 a = *(const float4*)(kp);
      float4 c = *(const float4*)(kp + 4);
      kb0.u[0] = pk2(a.x, a.y); kb0.u[1] = pk2(a.z, a.w);
      kb0.u[2] = pk2(c.x, c.y); kb0.u[3] = pk2(c.z, c.w);
      a = *(const float4*)(kp + 32);
      c = *(const float4*)(kp + 36);
      kb1.u[0] = pk2(a.x, a.y); kb1.u[1] = pk2(a.z, a.w);
      kb1.u[2] = pk2(c.x, c.y); kb1.u[3] = pk2(c.z, c.w);
    }
    f32x4 acc = {0.f, 0.f, 0.f, 0.f};
    acc = __builtin_amdgcn_mfma_f32_16x16x32_f16(qa0.v, kb0.v, acc, 0, 0, 0);
    acc = __builtin_amdgcn_mfma_f32_16x16x32_f16(qa1.v, kb1.v, acc, 0, 0, 0);
    #pragma unroll
    for (int r = 0; r < 4; ++r) {
      int q = g * 4 + r;
      __half hv = __float2half(acc[r]);
      unsigned bits = (unsigned)__half_as_ushort(hv);
      *(__half*)(lds + q * 4096 + (((unsigned)(s * 2)) ^ ((unsigned)((q & 7) << 4)))) = hv;
      atomicAdd(&binsU[q * 256 + (ou16_of(bits) >> 8)], 1u);
    }
  }
  __syncthreads();

  const float aw0 = AW[0], aw1 = AW[1], aw2 = AW[2];

  // ================= selection (wave w owns rows 4w..4w+3) =================
  unsigned d0a[4], d1a[4], d2a[4], k0a[4], k1a[4], k2a[4];
  float ma[4];
  #pragma unroll
  for (int rr = 0; rr < 4; ++rr) {
    int q = 4 * w + rr;
    const unsigned* hw = binsU + q * 256;
    unsigned p0 = sel_digit(hw, KSEL0, lane);
    unsigned p1 = sel_digit(hw, KSEL1, lane);
    unsigned p2 = sel_digit(hw, KSEL2, lane);
    d0a[rr] = p0 >> 16; k0a[rr] = p0 & 0xFFFFu;
    d1a[rr] = p1 >> 16; k1a[rr] = p1 & 0xFFFFu;
    d2a[rr] = p2 >> 16; k2a[rr] = p2 & 0xFFFFu;
    // row max upper bound from highest nonzero bin (softmax shift-invariant)
    uint4 hb = ((const uint4*)hw)[lane];
    int md = hb.w ? lane*4+3 : hb.z ? lane*4+2 : hb.y ? lane*4+1 : (hb.x ? lane*4 : -1);
    #pragma unroll
    for (int off = 1; off < 64; off <<= 1) md = max(md, __shfl_xor(md, off, 64));
    ma[rr] = __half2float(__ushort_as_half((unsigned short)ou16_inv((unsigned)md * 256u + 255u)));
  }

  unsigned* h2 = binsU + (4 * w) * 256;   // 768-entry wave-private region

  #pragma unroll
  for (int rr = 0; rr < 4; ++rr) {
    int q = 4 * w + rr;
    unsigned sw = (unsigned)((q & 7) << 4);
    char* rowp = lds + q * 4096;
    for (int i = lane; i < 768; i += 64) h2[i] = 0u;
    unsigned D0 = d0a[rr], D1 = d1a[rr], D2 = d2a[rr];
    // ---- radix round 2: restricted histograms ----
    for (int it = 0; it < 8; ++it) {
      uint2 dv = *(const uint2*)(rowp + (((unsigned)(it * 512 + lane * 8)) ^ sw));
      #pragma unroll
      for (int e = 0; e < 4; ++e) {
        unsigned bits = (((e & 2) ? dv.y : dv.x) >> ((e & 1) * 16)) & 0xFFFFu;
        unsigned ou = ou16_of(bits);
        unsigned hi = ou >> 8, lo = ou & 255u;
        if (hi == D0) atomicAdd(&h2[lo], 1u);
        if (hi == D1) atomicAdd(&h2[256 + lo], 1u);
        if (hi == D2) atomicAdd(&h2[512 + lo], 1u);
      }
    }
    unsigned T1o = (D0 << 8) | (sel_digit(h2,       k0a[rr], lane) >> 16);
    unsigned T2o = (D1 << 8) | (sel_digit(h2 + 256, k1a[rr], lane) >> 16);
    unsigned T3o = (D2 << 8) | (sel_digit(h2 + 512, k2a[rr], lane) >> 16);
    float m = ma[rr];
    // ---- Z-pass: store e = exp(s-m) in place ----
    float z1 = 0.f, z2 = 0.f, z3 = 0.f;
    for (int it = 0; it < 8; ++it) {
      char* ap = rowp + (((unsigned)(it * 512 + lane * 8)) ^ sw);
      uint2 dv = *(const uint2*)ap;
      unsigned nb[4];
      #pragma unroll
      for (int e = 0; e < 4; ++e) {
        unsigned bits = (((e & 2) ? dv.y : dv.x) >> ((e & 1) * 16)) & 0xFFFFu;
        float sv = __half2float(__ushort_as_half((unsigned short)bits));
        float ev = __expf(sv - m);
        unsigned ou = ou16_of(bits);
        if (ou >= T3o) z3 += ev;
        if (ou >= T2o) z2 += ev;
        if (ou >= T1o) z1 += ev;
        nb[e] = (unsigned)__half_as_ushort(__float2half(ev));
      }
      dv.x = nb[0] | (nb[1] << 16);
      dv.y = nb[2] | (nb[3] << 16);
      *(uint2*)ap = dv;
    }
    #pragma unroll
    for (int off = 1; off < 64; off <<= 1) {
      z1 += __shfl_xor(z1, off, 64);
      z2 += __shfl_xor(z2, off, 64);
      z3 += __shfl_xor(z3, off, 64);
    }
    float A3 = aw2 / z3;
    float A2 = aw1 / z2 + A3;
    float A1 = aw0 / z1 + A2;
    A1 *= WSC; A2 *= WSC; A3 *= WSC;
    float T1f = __half2float(__ushort_as_half((unsigned short)ou16_inv(T1o)));
    float T2f = __half2float(__ushort_as_half((unsigned short)ou16_inv(T2o)));
    float T3f = __half2float(__ushort_as_half((unsigned short)ou16_inv(T3o)));
    unsigned e1b = (unsigned)__half_as_ushort(__float2half(__expf(T1f - m)));
    unsigned e2b = (unsigned)__half_as_ushort(__float2half(__expf(T2f - m)));
    unsigned e3b = (unsigned)__half_as_ushort(__float2half(__expf(T3f - m)));
    // ---- weight pass: w = e * band_coef ----
    for (int it = 0; it < 8; ++it) {
      char* ap = rowp + (((unsigned)(it * 512 + lane * 8)) ^ sw);
      uint2 dv = *(const uint2*)ap;
      unsigned nb[4];
      #pragma unroll
      for (int e = 0; e < 4; ++e) {
        unsigned bits = (((e & 2) ? dv.y : dv.x) >> ((e & 1) * 16)) & 0xFFFFu;
        float ev = __half2float(__ushort_as_half((unsigned short)bits));
        float cf = (bits >= e1b) ? A1 : (bits >= e2b) ? A2 : (bits >= e3b) ? A3 : 0.f;
        nb[e] = (unsigned)__half_as_ushort(__float2half(ev * cf));
      }
      dv.x = nb[0] | (nb[1] << 16);
      dv.y = nb[2] | (nb[3] << 16);
      *(uint2*)ap = dv;
    }
  }
  __syncthreads();

  // ================= PV (MFMA): out^T[d][q] = sum_s Vt[d][s] * w[q][s] =================
  f32x4 oacc = {0.f, 0.f, 0.f, 0.f};
  const int dt = w * 16;
  const int u_ = lane >> 4;
  const int dq = (lane >> 2) & 3;
  const int r_ = lane & 3;
  const unsigned selv = (lane & 1) ? 0x03020706u : 0x05040100u;

  for (int ph = 0; ph < 16; ++ph) {
    __syncthreads();
    // stage Vt chunk: wave covers s_local [w*32, w*32+32), all 64 d
    #pragma unroll
    for (int sp = 0; sp < 2; ++sp) {
      #pragma unroll
      for (int p = 0; p < 4; ++p) {
        int sl = w * 32 + sp * 16 + u_ * 4;          // quad s base (local)
        int sg = ph * 128 + sl + r_;                 // global s for load
        int d0 = p * 16 + dq * 4;
        float4 f = *(const float4*)(Vb + (size_t)sg * 512 + d0);
        unsigned lo = pk2(f.x, f.y), hi = pk2(f.z, f.w);
        // 4x4 in-register transpose within lane quads
        unsigned tlo = shflx(lo, 1), thi = shflx(hi, 1);
        lo = __builtin_amdgcn_perm(tlo, lo, selv);
        hi = __builtin_amdgcn_perm(thi, hi, selv);
        unsigned t2lo = shflx(lo, 2), t2hi = shflx(hi, 2);
        unsigned Aw = (lane & 2) ? t2hi : lo;        // s: sl+0, sl+1
        unsigned Bw = (lane & 2) ? hi   : t2lo;      // s: sl+2, sl+3
        int d = d0 + r_;
        uint2 wv = {Aw, Bw};
        *(uint2*)(vtb + d * 256 + (((unsigned)(sl * 2)) ^ ((unsigned)((d & 7) << 4)))) = wv;
      }
    }
    __syncthreads();
    #pragma unroll
    for (int kc = 0; kc < 4; ++kc) {
      int d = dt + lx;
      f16x8 av = *(const f16x8*)(vtb + d * 256 +
                  (((unsigned)((kc * 32 + g * 8) * 2)) ^ ((unsigned)((d & 7) << 4))));
      int sgl = ph * 128 + kc * 32 + g * 8;
      f16x8 bv = *(const f16x8*)(lds + lx * 4096 +
                  (((unsigned)(sgl * 2)) ^ ((unsigned)((lx & 7) << 4))));
      oacc = __builtin_amdgcn_mfma_f32_16x16x32_f16(av, bv, oacc, 0, 0, 0);
    }
  }

  // C' lane: rows d = dt + 4g + r, col q = lx  ->  out[b][l0+lx][hh][d]
  float* op = Out + (((size_t)b * 2048 + l0 + lx) * 8 + hh) * 64 + dt + g * 4;
  float4 ov = { oacc[0] * (1.f/WSC), oacc[1] * (1.f/WSC),
                oacc[2] * (1.f/WSC), oacc[3] * (1.f/WSC) };
  *(float4*)op = ov;
}

extern "C" void kernel_launch(void* const* d_in, const int* in_sizes, int n_in,
                              void* d_out, int out_size, void* d_ws, size_t ws_size,
                              hipStream_t stream) {
  (void)in_sizes; (void)n_in; (void)d_ws; (void)ws_size; (void)out_size;
  const float* Q  = (const float*)d_in[0];
  const float* K  = (const float*)d_in[1];
  const float* V  = (const float*)d_in[2];
  const float* AW = (const float*)d_in[3];
  nma_kernel<<<dim3(4096), dim3(256), 0, stream>>>(Q, K, V, AW, (float*)d_out);
}

// Round 4
// 508.807 us; speedup vs baseline: 3.1906x; 1.4378x over previous
//
#include <hip/hip_runtime.h>
#include <hip/hip_fp16.h>

typedef _Float16 f16x8 __attribute__((ext_vector_type(8)));
typedef float f32x4 __attribute__((ext_vector_type(4)));

#define KSEL0 1372u   // int(2048*0.67)
#define KSEL1 1536u   // int(2048*0.75)
#define KSEL2 1638u   // int(2048*0.80)
#define WSC 16.0f

__device__ __forceinline__ unsigned ou16_of(unsigned hb) {
  return hb ^ ((hb & 0x8000u) ? 0xFFFFu : 0x8000u);
}
__device__ __forceinline__ unsigned ou16_inv(unsigned ou) {
  return (ou & 0x8000u) ? (ou ^ 0x8000u) : (ou ^ 0xFFFFu);
}
__device__ __forceinline__ unsigned pk2(float a, float b) {
  auto h = __builtin_amdgcn_cvt_pkrtz(a, b);
  return __builtin_bit_cast(unsigned, h);
}
__device__ __forceinline__ unsigned shflx(unsigned v, int m) {
  return (unsigned)__shfl_xor((int)v, m, 64);
}

// exact k-th-largest digit select on a 256-bin histogram (wave-collective)
__device__ __forceinline__ unsigned sel_digit(const unsigned* histw, unsigned k, int lane) {
  uint4 h = ((const uint4*)histw)[lane];
  unsigned s4 = h.x + h.y + h.z + h.w;
  unsigned p = s4;
  #pragma unroll
  for (int off = 1; off < 64; off <<= 1) {
    int sl = lane + off;
    unsigned t = (unsigned)__shfl((int)p, sl < 64 ? sl : lane, 64);
    p += (sl < 64) ? t : 0u;
  }
  unsigned a3 = p - s4;
  unsigned a2 = a3 + h.w;
  unsigned a1 = a2 + h.z;
  unsigned a0 = a1 + h.y;
  int d = -1; unsigned nk = 0;
  if (a3 < k && a3 + h.w >= k)      { d = 4*lane+3; nk = k - a3; }
  else if (a2 < k && a2 + h.z >= k) { d = 4*lane+2; nk = k - a2; }
  else if (a1 < k && a1 + h.y >= k) { d = 4*lane+1; nk = k - a1; }
  else if (a0 < k && a0 + h.x >= k) { d = 4*lane+0; nk = k - a0; }
  unsigned long long mb = __ballot(d >= 0);
  int src = __ffsll(mb) - 1;
  unsigned pack = ((unsigned)d << 16) | nk;
  return (unsigned)__shfl((int)pack, src, 64);
}

// ---------- prep: K fp32 -> Kh fp16 [bh][s][e] ----------
extern "C" __global__ __launch_bounds__(256)
void prep_k(const float* __restrict__ K, unsigned short* __restrict__ Kh) {
  int idx = blockIdx.x * 256 + threadIdx.x;       // (bh, s, ec)
  int ec = idx & 7;
  int s  = (idx >> 3) & 2047;
  int bh = idx >> 14;
  int b = bh >> 3, h = bh & 7;
  const float* src = K + (((size_t)b * 2048 + s) * 8 + h) * 64 + ec * 8;
  float4 a = *(const float4*)src;
  float4 c = *(const float4*)(src + 4);
  uint4 val = { pk2(a.x, a.y), pk2(a.z, a.w), pk2(c.x, c.y), pk2(c.z, c.w) };
  *(uint4*)(Kh + (size_t)idx * 8) = val;
}

// ---------- prep: V fp32 -> Vt fp16 [bh][d][s] (transposed) ----------
extern "C" __global__ __launch_bounds__(256)
void prep_v(const float* __restrict__ V, unsigned short* __restrict__ Vt) {
  const int tid  = threadIdx.x;
  const int w    = tid >> 6;
  const int lane = tid & 63;
  const int u_   = lane >> 4;
  const int dq   = (lane >> 2) & 3;
  const int r_   = lane & 3;
  const unsigned selv = (lane & 1) ? 0x03020706u : 0x05040100u;

  int bh = blockIdx.x >> 4;            // 32 bh
  int s0 = (blockIdx.x & 15) * 128;    // 16 s-chunks of 128
  int b = bh >> 3, h = bh & 7;
  const float* Vb = V + ((size_t)b * 2048 * 8 + h) * 64;
  unsigned short* Vo = Vt + (size_t)bh * 64 * 2048;

  #pragma unroll
  for (int sp = 0; sp < 2; ++sp) {
    #pragma unroll
    for (int p = 0; p < 4; ++p) {
      int sl = w * 32 + sp * 16 + u_ * 4;
      int sg = s0 + sl + r_;
      int d0 = p * 16 + dq * 4;
      float4 f = *(const float4*)(Vb + (size_t)sg * 512 + d0);
      unsigned lo = pk2(f.x, f.y), hi = pk2(f.z, f.w);
      unsigned tlo = shflx(lo, 1), thi = shflx(hi, 1);
      lo = __builtin_amdgcn_perm(tlo, lo, selv);
      hi = __builtin_amdgcn_perm(thi, hi, selv);
      unsigned t2lo = shflx(lo, 2), t2hi = shflx(hi, 2);
      unsigned Aw = (lane & 2) ? t2hi : lo;        // s: sl+0, sl+1
      unsigned Bw = (lane & 2) ? hi   : t2lo;      // s: sl+2, sl+3
      int d = d0 + r_;
      uint2 wv = {Aw, Bw};
      *(uint2*)(Vo + (size_t)d * 2048 + s0 + sl) = wv;
    }
  }
}

// ---------- main ----------
extern "C" __global__ __launch_bounds__(256, 2)
void nma_kernel(const float* __restrict__ Q, const unsigned short* __restrict__ Kh,
                const unsigned short* __restrict__ Vt, const float* __restrict__ AW,
                float* __restrict__ Out)
{
  // LDS: [0,64K) sc[16 rows][2048] fp16, swizzled byte^=((q&7)<<4); [64K,80K) hist
  __shared__ __align__(16) char lds[81920];
  unsigned* binsU = (unsigned*)(lds + 65536);

  const int tid  = threadIdx.x;
  const int w    = tid >> 6;
  const int lane = tid & 63;
  const int g    = lane >> 4;
  const int lx   = lane & 15;

  int bid = blockIdx.x;
  int lb  = (bid & 7) * 512 + (bid >> 3);
  int bh  = lb >> 7;
  int b   = bh >> 3, hh = bh & 7;
  int l0  = (lb & 127) << 4;

  const float* Qb = Q + (((size_t)b * 2048 + l0) * 8 + hh) * 64;
  const unsigned short* Khb = Kh + (size_t)bh * 2048 * 64;
  const unsigned short* Vtb = Vt + (size_t)bh * 64 * 2048;

  {
    uint4 z4 = {0u,0u,0u,0u};
    uint4* p = (uint4*)binsU;
    #pragma unroll
    for (int i = 0; i < 4; ++i) p[tid + 256*i] = z4;
  }

  union FU { f16x8 v; unsigned u[4]; };
  FU qa0, qa1;
  {
    const float* qp = Qb + (size_t)lx * 512 + g * 8;
    float4 a = *(const float4*)(qp);
    float4 c = *(const float4*)(qp + 4);
    qa0.u[0] = pk2(a.x*0.125f, a.y*0.125f); qa0.u[1] = pk2(a.z*0.125f, a.w*0.125f);
    qa0.u[2] = pk2(c.x*0.125f, c.y*0.125f); qa0.u[3] = pk2(c.z*0.125f, c.w*0.125f);
    a = *(const float4*)(qp + 32);
    c = *(const float4*)(qp + 36);
    qa1.u[0] = pk2(a.x*0.125f, a.y*0.125f); qa1.u[1] = pk2(a.z*0.125f, a.w*0.125f);
    qa1.u[2] = pk2(c.x*0.125f, c.y*0.125f); qa1.u[3] = pk2(c.z*0.125f, c.w*0.125f);
  }
  __syncthreads();

  // ========== QK^T (MFMA, Kh direct from L2) + fused hist1 ==========
  for (int t = 0; t < 32; ++t) {
    int ct = t * 4 + w;
    int s  = ct * 16 + lx;
    const unsigned short* kp = Khb + (size_t)s * 64 + g * 8;
    f16x8 kb0 = *(const f16x8*)(kp);
    f16x8 kb1 = *(const f16x8*)(kp + 32);
    f32x4 acc = {0.f, 0.f, 0.f, 0.f};
    acc = __builtin_amdgcn_mfma_f32_16x16x32_f16(qa0.v, kb0, acc, 0, 0, 0);
    acc = __builtin_amdgcn_mfma_f32_16x16x32_f16(qa1.v, kb1, acc, 0, 0, 0);
    #pragma unroll
    for (int r = 0; r < 4; ++r) {
      int q = g * 4 + r;
      __half hv = __float2half(acc[r]);
      unsigned bits = (unsigned)__half_as_ushort(hv);
      *(__half*)(lds + q * 4096 + (((unsigned)(s * 2)) ^ ((unsigned)((q & 7) << 4)))) = hv;
      atomicAdd(&binsU[q * 256 + (ou16_of(bits) >> 8)], 1u);
    }
  }
  __syncthreads();

  const float aw0 = AW[0], aw1 = AW[1], aw2 = AW[2];

  // ========== selection (wave w owns rows 4w..4w+3) ==========
  unsigned d0a[4], d1a[4], d2a[4], k0a[4], k1a[4], k2a[4];
  float ma[4];
  #pragma unroll
  for (int rr = 0; rr < 4; ++rr) {
    int q = 4 * w + rr;
    const unsigned* hw = binsU + q * 256;
    unsigned p0 = sel_digit(hw, KSEL0, lane);
    unsigned p1 = sel_digit(hw, KSEL1, lane);
    unsigned p2 = sel_digit(hw, KSEL2, lane);
    d0a[rr] = p0 >> 16; k0a[rr] = p0 & 0xFFFFu;
    d1a[rr] = p1 >> 16; k1a[rr] = p1 & 0xFFFFu;
    d2a[rr] = p2 >> 16; k2a[rr] = p2 & 0xFFFFu;
    uint4 hb = ((const uint4*)hw)[lane];
    int md = hb.w ? lane*4+3 : hb.z ? lane*4+2 : hb.y ? lane*4+1 : (hb.x ? lane*4 : -1);
    #pragma unroll
    for (int off = 1; off < 64; off <<= 1) md = max(md, __shfl_xor(md, off, 64));
    ma[rr] = __half2float(__ushort_as_half((unsigned short)ou16_inv((unsigned)md * 256u + 255u)));
  }

  unsigned* h2 = binsU + (4 * w) * 256;

  #pragma unroll
  for (int rr = 0; rr < 4; ++rr) {
    int q = 4 * w + rr;
    unsigned sw = (unsigned)((q & 7) << 4);
    char* rowp = lds + q * 4096;
    for (int i = lane; i < 768; i += 64) h2[i] = 0u;
    unsigned D0 = d0a[rr], D1 = d1a[rr], D2 = d2a[rr];
    for (int it = 0; it < 8; ++it) {
      uint2 dv = *(const uint2*)(rowp + (((unsigned)(it * 512 + lane * 8)) ^ sw));
      #pragma unroll
      for (int e = 0; e < 4; ++e) {
        unsigned bits = (((e & 2) ? dv.y : dv.x) >> ((e & 1) * 16)) & 0xFFFFu;
        unsigned ou = ou16_of(bits);
        unsigned hi = ou >> 8, lo = ou & 255u;
        if (hi == D0) atomicAdd(&h2[lo], 1u);
        if (hi == D1) atomicAdd(&h2[256 + lo], 1u);
        if (hi == D2) atomicAdd(&h2[512 + lo], 1u);
      }
    }
    unsigned T1o = (D0 << 8) | (sel_digit(h2,       k0a[rr], lane) >> 16);
    unsigned T2o = (D1 << 8) | (sel_digit(h2 + 256, k1a[rr], lane) >> 16);
    unsigned T3o = (D2 << 8) | (sel_digit(h2 + 512, k2a[rr], lane) >> 16);
    float m = ma[rr];
    float z1 = 0.f, z2 = 0.f, z3 = 0.f;
    for (int it = 0; it < 8; ++it) {
      char* ap = rowp + (((unsigned)(it * 512 + lane * 8)) ^ sw);
      uint2 dv = *(const uint2*)ap;
      unsigned nb[4];
      #pragma unroll
      for (int e = 0; e < 4; ++e) {
        unsigned bits = (((e & 2) ? dv.y : dv.x) >> ((e & 1) * 16)) & 0xFFFFu;
        float sv = __half2float(__ushort_as_half((unsigned short)bits));
        float ev = __expf(sv - m);
        unsigned ou = ou16_of(bits);
        if (ou >= T3o) z3 += ev;
        if (ou >= T2o) z2 += ev;
        if (ou >= T1o) z1 += ev;
        nb[e] = (unsigned)__half_as_ushort(__float2half(ev));
      }
      dv.x = nb[0] | (nb[1] << 16);
      dv.y = nb[2] | (nb[3] << 16);
      *(uint2*)ap = dv;
    }
    #pragma unroll
    for (int off = 1; off < 64; off <<= 1) {
      z1 += __shfl_xor(z1, off, 64);
      z2 += __shfl_xor(z2, off, 64);
      z3 += __shfl_xor(z3, off, 64);
    }
    float A3 = aw2 / z3;
    float A2 = aw1 / z2 + A3;
    float A1 = aw0 / z1 + A2;
    A1 *= WSC; A2 *= WSC; A3 *= WSC;
    float T1f = __half2float(__ushort_as_half((unsigned short)ou16_inv(T1o)));
    float T2f = __half2float(__ushort_as_half((unsigned short)ou16_inv(T2o)));
    float T3f = __half2float(__ushort_as_half((unsigned short)ou16_inv(T3o)));
    unsigned e1b = (unsigned)__half_as_ushort(__float2half(__expf(T1f - m)));
    unsigned e2b = (unsigned)__half_as_ushort(__float2half(__expf(T2f - m)));
    unsigned e3b = (unsigned)__half_as_ushort(__float2half(__expf(T3f - m)));
    for (int it = 0; it < 8; ++it) {
      char* ap = rowp + (((unsigned)(it * 512 + lane * 8)) ^ sw);
      uint2 dv = *(const uint2*)ap;
      unsigned nb[4];
      #pragma unroll
      for (int e = 0; e < 4; ++e) {
        unsigned bits = (((e & 2) ? dv.y : dv.x) >> ((e & 1) * 16)) & 0xFFFFu;
        float ev = __half2float(__ushort_as_half((unsigned short)bits));
        float cf = (bits >= e1b) ? A1 : (bits >= e2b) ? A2 : (bits >= e3b) ? A3 : 0.f;
        nb[e] = (unsigned)__half_as_ushort(__float2half(ev * cf));
      }
      dv.x = nb[0] | (nb[1] << 16);
      dv.y = nb[2] | (nb[3] << 16);
      *(uint2*)ap = dv;
    }
  }
  __syncthreads();

  // ========== PV (MFMA): out^T[d][q] = sum_s Vt[d][s] * w[q][s] ==========
  f32x4 oacc = {0.f, 0.f, 0.f, 0.f};
  const int dt = w * 16;
  const int d  = dt + lx;
  const unsigned short* vp = Vtb + (size_t)d * 2048 + g * 8;
  const char* bp = lds + lx * 4096;
  const unsigned bswz = (unsigned)((lx & 7) << 4);

  #pragma unroll 8
  for (int kc = 0; kc < 64; ++kc) {
    f16x8 av = *(const f16x8*)(vp + kc * 32);
    f16x8 bv = *(const f16x8*)(bp + (((unsigned)((kc * 32 + g * 8) * 2)) ^ bswz));
    oacc = __builtin_amdgcn_mfma_f32_16x16x32_f16(av, bv, oacc, 0, 0, 0);
  }

  float* op = Out + (((size_t)b * 2048 + l0 + lx) * 8 + hh) * 64 + dt + g * 4;
  float4 ov = { oacc[0] * (1.f/WSC), oacc[1] * (1.f/WSC),
                oacc[2] * (1.f/WSC), oacc[3] * (1.f/WSC) };
  *(float4*)op = ov;
}

extern "C" void kernel_launch(void* const* d_in, const int* in_sizes, int n_in,
                              void* d_out, int out_size, void* d_ws, size_t ws_size,
                              hipStream_t stream) {
  (void)in_sizes; (void)n_in; (void)out_size; (void)ws_size;
  const float* Q  = (const float*)d_in[0];
  const float* K  = (const float*)d_in[1];
  const float* V  = (const float*)d_in[2];
  const float* AW = (const float*)d_in[3];
  unsigned short* Kh = (unsigned short*)d_ws;                    // 8.4 MB
  unsigned short* Vt = (unsigned short*)((char*)d_ws + 8388608); // 8.4 MB
  prep_k<<<dim3(2048), dim3(256), 0, stream>>>(K, Kh);
  prep_v<<<dim3(512),  dim3(256), 0, stream>>>(V, Vt);
  nma_kernel<<<dim3(4096), dim3(256), 0, stream>>>(Q, Kh, Vt, AW, (float*)d_out);
}

// Round 5
// 379.328 us; speedup vs baseline: 4.2797x; 1.3413x over previous
//
#include <hip/hip_runtime.h>
#include <hip/hip_fp16.h>

typedef _Float16 f16x8 __attribute__((ext_vector_type(8)));
typedef float f32x4 __attribute__((ext_vector_type(4)));

#define KSEL0 1372u   // int(2048*0.67)
#define KSEL1 1536u   // int(2048*0.75)
#define KSEL2 1638u   // int(2048*0.80)
#define WSC 16.0f

__device__ __forceinline__ unsigned ou16_of(unsigned hb) {
  return hb ^ ((hb & 0x8000u) ? 0xFFFFu : 0x8000u);
}
__device__ __forceinline__ unsigned ou16_inv(unsigned ou) {
  return (ou & 0x8000u) ? (ou ^ 0x8000u) : (ou ^ 0xFFFFu);
}
__device__ __forceinline__ unsigned pk2(float a, float b) {
  auto h = __builtin_amdgcn_cvt_pkrtz(a, b);
  return __builtin_bit_cast(unsigned, h);
}
__device__ __forceinline__ unsigned shflx(unsigned v, int m) {
  return (unsigned)__shfl_xor((int)v, m, 64);
}

// exact k-th-largest digit select on a 256-bin histogram (wave-collective).
// hist entries may pack two counts (shift selects 0/16). returns (digit<<16)|remk
__device__ __forceinline__ unsigned sel_digit_s(const unsigned* histw, unsigned k,
                                                int lane, int shift) {
  uint4 hr = ((const uint4*)histw)[lane];
  unsigned hx = (hr.x >> shift) & 0xFFFFu;
  unsigned hy = (hr.y >> shift) & 0xFFFFu;
  unsigned hz = (hr.z >> shift) & 0xFFFFu;
  unsigned hw_ = (hr.w >> shift) & 0xFFFFu;
  unsigned s4 = hx + hy + hz + hw_;
  unsigned p = s4;
  #pragma unroll
  for (int off = 1; off < 64; off <<= 1) {
    int sl = lane + off;
    unsigned t = (unsigned)__shfl((int)p, sl < 64 ? sl : lane, 64);
    p += (sl < 64) ? t : 0u;
  }
  unsigned a3 = p - s4;
  unsigned a2 = a3 + hw_;
  unsigned a1 = a2 + hz;
  unsigned a0 = a1 + hy;
  int d = -1; unsigned nk = 0;
  if (a3 < k && a3 + hw_ >= k)      { d = 4*lane+3; nk = k - a3; }
  else if (a2 < k && a2 + hz >= k)  { d = 4*lane+2; nk = k - a2; }
  else if (a1 < k && a1 + hy >= k)  { d = 4*lane+1; nk = k - a1; }
  else if (a0 < k && a0 + hx >= k)  { d = 4*lane+0; nk = k - a0; }
  unsigned long long mb = __ballot(d >= 0);
  int src = __ffsll(mb) - 1;
  unsigned pack = ((unsigned)d << 16) | nk;
  return (unsigned)__shfl((int)pack, src, 64);
}

// ---------- prep: K fp32 -> Kh fp16 [bh][s][e] ----------
extern "C" __global__ __launch_bounds__(256)
void prep_k(const float* __restrict__ K, unsigned short* __restrict__ Kh) {
  int idx = blockIdx.x * 256 + threadIdx.x;
  int ec = idx & 7;
  int s  = (idx >> 3) & 2047;
  int bh = idx >> 14;
  int b = bh >> 3, h = bh & 7;
  const float* src = K + (((size_t)b * 2048 + s) * 8 + h) * 64 + ec * 8;
  float4 a = *(const float4*)src;
  float4 c = *(const float4*)(src + 4);
  uint4 val = { pk2(a.x, a.y), pk2(a.z, a.w), pk2(c.x, c.y), pk2(c.z, c.w) };
  *(uint4*)(Kh + (size_t)idx * 8) = val;
}

// ---------- prep: V fp32 -> Vt fp16 [bh][d][s] (transposed) ----------
extern "C" __global__ __launch_bounds__(256)
void prep_v(const float* __restrict__ V, unsigned short* __restrict__ Vt) {
  const int tid  = threadIdx.x;
  const int w    = tid >> 6;
  const int lane = tid & 63;
  const int u_   = lane >> 4;
  const int dq   = (lane >> 2) & 3;
  const int r_   = lane & 3;
  const unsigned selv = (lane & 1) ? 0x03020706u : 0x05040100u;

  int bh = blockIdx.x >> 4;
  int s0 = (blockIdx.x & 15) * 128;
  int b = bh >> 3, h = bh & 7;
  const float* Vb = V + ((size_t)b * 2048 * 8 + h) * 64;
  unsigned short* Vo = Vt + (size_t)bh * 64 * 2048;

  #pragma unroll
  for (int sp = 0; sp < 2; ++sp) {
    #pragma unroll
    for (int p = 0; p < 4; ++p) {
      int sl = w * 32 + sp * 16 + u_ * 4;
      int sg = s0 + sl + r_;
      int d0 = p * 16 + dq * 4;
      float4 f = *(const float4*)(Vb + (size_t)sg * 512 + d0);
      unsigned lo = pk2(f.x, f.y), hi = pk2(f.z, f.w);
      unsigned tlo = shflx(lo, 1), thi = shflx(hi, 1);
      lo = __builtin_amdgcn_perm(tlo, lo, selv);
      hi = __builtin_amdgcn_perm(thi, hi, selv);
      unsigned t2lo = shflx(lo, 2), t2hi = shflx(hi, 2);
      unsigned Aw = (lane & 2) ? t2hi : lo;
      unsigned Bw = (lane & 2) ? hi   : t2lo;
      int d = d0 + r_;
      uint2 wv = {Aw, Bw};
      *(uint2*)(Vo + (size_t)d * 2048 + s0 + sl) = wv;
    }
  }
}

// ---------- main: 512 threads (8 waves), 16 q-rows ----------
extern "C" __global__ __launch_bounds__(512, 4)
void nma_kernel(const float* __restrict__ Q, const unsigned short* __restrict__ Kh,
                const unsigned short* __restrict__ Vt, const float* __restrict__ AW,
                float* __restrict__ Out)
{
  // LDS: [0,64K) sc[16 rows][2048] fp16, row q byte-swizzled ^(((q&7)<<4)|((q&8)<<3))
  //      [64K,80K) work: hist1[16][256] -> h2[8 waves][512] -> PV partials (8KB)
  __shared__ __align__(16) char lds[81920];
  unsigned* work = (unsigned*)(lds + 65536);

  const int tid  = threadIdx.x;
  const int w    = tid >> 6;      // wave 0..7
  const int lane = tid & 63;
  const int g    = lane >> 4;
  const int lx   = lane & 15;

  // XCD-aware bijective swizzle (4096 % 8 == 0)
  int bid = blockIdx.x;
  int lb  = (bid & 7) * 512 + (bid >> 3);
  int bh  = lb >> 7;
  int b   = bh >> 3, hh = bh & 7;
  int l0  = (lb & 127) << 4;

  const float* Qb = Q + (((size_t)b * 2048 + l0) * 8 + hh) * 64;
  const unsigned short* Khb = Kh + (size_t)bh * 2048 * 64;
  const unsigned short* Vtb = Vt + (size_t)bh * 64 * 2048;

  // zero hist1 (4096 u32)
  {
    uint4 z4 = {0u,0u,0u,0u};
    uint4* p = (uint4*)work;
    p[tid] = z4;
    p[tid + 512] = z4;
  }

  // Q B-frag (col=lx, k=g*8..; two K-halves), scale 1/8 folded
  union FU { f16x8 v; unsigned u[4]; };
  FU qa0, qa1;
  {
    const float* qp = Qb + (size_t)lx * 512 + g * 8;
    float4 a = *(const float4*)(qp);
    float4 c = *(const float4*)(qp + 4);
    qa0.u[0] = pk2(a.x*0.125f, a.y*0.125f); qa0.u[1] = pk2(a.z*0.125f, a.w*0.125f);
    qa0.u[2] = pk2(c.x*0.125f, c.y*0.125f); qa0.u[3] = pk2(c.z*0.125f, c.w*0.125f);
    a = *(const float4*)(qp + 32);
    c = *(const float4*)(qp + 36);
    qa1.u[0] = pk2(a.x*0.125f, a.y*0.125f); qa1.u[1] = pk2(a.z*0.125f, a.w*0.125f);
    qa1.u[2] = pk2(c.x*0.125f, c.y*0.125f); qa1.u[3] = pk2(c.z*0.125f, c.w*0.125f);
  }
  __syncthreads();

  // ===== QK^T transposed: D[s][q] = mfma(A=K, B=Q); lane holds 4 consecutive s for q=lx =====
  const unsigned swl = (((unsigned)(lx & 7)) << 4) | (((unsigned)(lx & 8)) << 3);
  unsigned* hq = work + lx * 256;
  #pragma unroll 2
  for (int t = 0; t < 16; ++t) {
    int s0 = (t * 8 + w) * 16;
    const unsigned short* kp = Khb + (size_t)(s0 + lx) * 64 + g * 8;
    f16x8 kb0 = *(const f16x8*)(kp);
    f16x8 kb1 = *(const f16x8*)(kp + 32);
    f32x4 acc = {0.f, 0.f, 0.f, 0.f};
    acc = __builtin_amdgcn_mfma_f32_16x16x32_f16(kb0, qa0.v, acc, 0, 0, 0);
    acc = __builtin_amdgcn_mfma_f32_16x16x32_f16(kb1, qa1.v, acc, 0, 0, 0);
    unsigned u0 = pk2(acc[0], acc[1]);
    unsigned u1 = pk2(acc[2], acc[3]);
    uint2 wv = {u0, u1};
    *(uint2*)(lds + lx * 4096 + (((unsigned)(s0 * 2 + g * 8)) ^ swl)) = wv;
    atomicAdd(&hq[ou16_of(u0 & 0xFFFFu) >> 8], 1u);
    atomicAdd(&hq[ou16_of(u0 >> 16) >> 8], 1u);
    atomicAdd(&hq[ou16_of(u1 & 0xFFFFu) >> 8], 1u);
    atomicAdd(&hq[ou16_of(u1 >> 16) >> 8], 1u);
  }
  __syncthreads();

  const float aw0 = AW[0], aw1 = AW[1], aw2 = AW[2];

  // ===== round 1: wave w owns rows 2w, 2w+1 =====
  unsigned d0a[2], d1a[2], d2a[2], k0a[2], k1a[2], k2a[2];
  float ma[2];
  #pragma unroll
  for (int rr = 0; rr < 2; ++rr) {
    int q = 2 * w + rr;
    const unsigned* hw1 = work + q * 256;
    unsigned p0 = sel_digit_s(hw1, KSEL0, lane, 0);
    unsigned p1 = sel_digit_s(hw1, KSEL1, lane, 0);
    unsigned p2 = sel_digit_s(hw1, KSEL2, lane, 0);
    d0a[rr] = p0 >> 16; k0a[rr] = p0 & 0xFFFFu;
    d1a[rr] = p1 >> 16; k1a[rr] = p1 & 0xFFFFu;
    d2a[rr] = p2 >> 16; k2a[rr] = p2 & 0xFFFFu;
    uint4 hb = ((const uint4*)hw1)[lane];
    int md = hb.w ? lane*4+3 : hb.z ? lane*4+2 : hb.y ? lane*4+1 : (hb.x ? lane*4 : -1);
    #pragma unroll
    for (int off = 1; off < 64; off <<= 1) md = max(md, __shfl_xor(md, off, 64));
    ma[rr] = __half2float(__ushort_as_half((unsigned short)ou16_inv((unsigned)md * 256u + 255u)));
  }

  // ===== round 2 + Z + weight (h2 overlays this wave's own hist1 rows) =====
  unsigned* hw2 = work + w * 512;
  #pragma unroll 1
  for (int rr = 0; rr < 2; ++rr) {
    int q = 2 * w + rr;
    const unsigned swq = (((unsigned)(q & 7)) << 4) | (((unsigned)(q & 8)) << 3);
    char* rowp = lds + q * 4096;
    for (int i = lane; i < 512; i += 64) hw2[i] = 0u;
    unsigned D0 = d0a[rr], D1 = d1a[rr], D2 = d2a[rr];
    // packed count pass: D0 low16, D1 high16, D2 separate
    for (int it = 0; it < 4; ++it) {
      uint4 dv = *(const uint4*)(rowp + (((unsigned)(it * 1024 + lane * 16)) ^ swq));
      unsigned ws[4] = {dv.x, dv.y, dv.z, dv.w};
      #pragma unroll
      for (int p = 0; p < 4; ++p) {
        #pragma unroll
        for (int hp = 0; hp < 2; ++hp) {
          unsigned bits = (ws[p] >> (hp * 16)) & 0xFFFFu;
          unsigned ou = ou16_of(bits);
          unsigned hi = ou >> 8, lo = ou & 255u;
          unsigned add = (hi == D0 ? 1u : 0u) | (hi == D1 ? 0x10000u : 0u);
          if (add) atomicAdd(&hw2[lo], add);
          if (hi == D2) atomicAdd(&hw2[256 + lo], 1u);
        }
      }
    }
    unsigned T1o = (D0 << 8) | (sel_digit_s(hw2,       k0a[rr], lane, 0)  >> 16);
    unsigned T2o = (D1 << 8) | (sel_digit_s(hw2,       k1a[rr], lane, 16) >> 16);
    unsigned T3o = (D2 << 8) | (sel_digit_s(hw2 + 256, k2a[rr], lane, 0)  >> 16);
    float m = ma[rr];
    // Z pass: store e = exp(s-m) in place (RTZ pack, consistent with thresholds)
    float z1 = 0.f, z2 = 0.f, z3 = 0.f;
    for (int it = 0; it < 4; ++it) {
      char* ap = rowp + (((unsigned)(it * 1024 + lane * 16)) ^ swq);
      uint4 dv = *(const uint4*)ap;
      unsigned ws[4] = {dv.x, dv.y, dv.z, dv.w};
      uint4 nv;
      unsigned no[4];
      #pragma unroll
      for (int p = 0; p < 4; ++p) {
        unsigned b0 = ws[p] & 0xFFFFu, b1 = ws[p] >> 16;
        float s0 = __half2float(__ushort_as_half((unsigned short)b0));
        float s1 = __half2float(__ushort_as_half((unsigned short)b1));
        float e0 = __expf(s0 - m), e1 = __expf(s1 - m);
        unsigned o0 = ou16_of(b0), o1 = ou16_of(b1);
        if (o0 >= T3o) z3 += e0;
        if (o0 >= T2o) z2 += e0;
        if (o0 >= T1o) z1 += e0;
        if (o1 >= T3o) z3 += e1;
        if (o1 >= T2o) z2 += e1;
        if (o1 >= T1o) z1 += e1;
        no[p] = pk2(e0, e1);
      }
      nv.x = no[0]; nv.y = no[1]; nv.z = no[2]; nv.w = no[3];
      *(uint4*)ap = nv;
    }
    #pragma unroll
    for (int off = 1; off < 64; off <<= 1) {
      z1 += __shfl_xor(z1, off, 64);
      z2 += __shfl_xor(z2, off, 64);
      z3 += __shfl_xor(z3, off, 64);
    }
    float A3 = aw2 / z3;
    float A2 = aw1 / z2 + A3;
    float A1 = aw0 / z1 + A2;
    A1 *= WSC; A2 *= WSC; A3 *= WSC;
    float T1f = __half2float(__ushort_as_half((unsigned short)ou16_inv(T1o)));
    float T2f = __half2float(__ushort_as_half((unsigned short)ou16_inv(T2o)));
    float T3f = __half2float(__ushort_as_half((unsigned short)ou16_inv(T3o)));
    unsigned e1b = pk2(__expf(T1f - m), 0.f) & 0xFFFFu;
    unsigned e2b = pk2(__expf(T2f - m), 0.f) & 0xFFFFu;
    unsigned e3b = pk2(__expf(T3f - m), 0.f) & 0xFFFFu;
    // weight pass: w = e * band_coef
    for (int it = 0; it < 4; ++it) {
      char* ap = rowp + (((unsigned)(it * 1024 + lane * 16)) ^ swq);
      uint4 dv = *(const uint4*)ap;
      unsigned ws[4] = {dv.x, dv.y, dv.z, dv.w};
      uint4 nv;
      unsigned no[4];
      #pragma unroll
      for (int p = 0; p < 4; ++p) {
        unsigned b0 = ws[p] & 0xFFFFu, b1 = ws[p] >> 16;
        float e0 = __half2float(__ushort_as_half((unsigned short)b0));
        float e1 = __half2float(__ushort_as_half((unsigned short)b1));
        float c0 = (b0 >= e1b) ? A1 : (b0 >= e2b) ? A2 : (b0 >= e3b) ? A3 : 0.f;
        float c1 = (b1 >= e1b) ? A1 : (b1 >= e2b) ? A2 : (b1 >= e3b) ? A3 : 0.f;
        no[p] = pk2(e0 * c0, e1 * c1);
      }
      nv.x = no[0]; nv.y = no[1]; nv.z = no[2]; nv.w = no[3];
      *(uint4*)ap = nv;
    }
  }
  __syncthreads();

  // ===== PV: out^T[d][q] = sum_s Vt[d][s] * w[q][s]; 8 waves = 4 d-tiles x 2 s-halves =====
  f32x4 oacc = {0.f, 0.f, 0.f, 0.f};
  const int dt = (w >> 1) * 16;
  const int sh = w & 1;
  const unsigned short* vp = Vtb + (size_t)(dt + lx) * 2048 + sh * 1024 + g * 8;
  const char* bp = lds + lx * 4096;

  #pragma unroll 8
  for (int kc = 0; kc < 32; ++kc) {
    f16x8 av = *(const f16x8*)(vp + kc * 32);
    unsigned sb = (unsigned)((sh * 1024 + kc * 32 + g * 8) * 2);
    f16x8 bv = *(const f16x8*)(bp + (sb ^ swl));
    oacc = __builtin_amdgcn_mfma_f32_16x16x32_f16(av, bv, oacc, 0, 0, 0);
  }

  float* pbuf = (float*)work;   // 8 waves x 256 floats = 8KB
  *(f32x4*)(pbuf + w * 256 + lx * 16 + g * 4) = oacc;
  __syncthreads();
  if (w < 4) {
    const float* pa = pbuf + (2 * w) * 256 + lx * 16 + g * 4;
    float4 ra = *(const float4*)pa;
    float4 rb = *(const float4*)(pa + 256);
    float* op = Out + (((size_t)b * 2048 + l0 + lx) * 8 + hh) * 64 + w * 16 + g * 4;
    float4 ov = { (ra.x + rb.x) * (1.f/WSC), (ra.y + rb.y) * (1.f/WSC),
                  (ra.z + rb.z) * (1.f/WSC), (ra.w + rb.w) * (1.f/WSC) };
    *(float4*)op = ov;
  }
}

extern "C" void kernel_launch(void* const* d_in, const int* in_sizes, int n_in,
                              void* d_out, int out_size, void* d_ws, size_t ws_size,
                              hipStream_t stream) {
  (void)in_sizes; (void)n_in; (void)out_size; (void)ws_size;
  const float* Q  = (const float*)d_in[0];
  const float* K  = (const float*)d_in[1];
  const float* V  = (const float*)d_in[2];
  const float* AW = (const float*)d_in[3];
  unsigned short* Kh = (unsigned short*)d_ws;                    // 8.4 MB
  unsigned short* Vt = (unsigned short*)((char*)d_ws + 8388608); // 8.4 MB
  prep_k<<<dim3(2048), dim3(256), 0, stream>>>(K, Kh);
  prep_v<<<dim3(512),  dim3(256), 0, stream>>>(V, Vt);
  nma_kernel<<<dim3(4096), dim3(512), 0, stream>>>(Q, Kh, Vt, AW, (float*)d_out);
}